// Round 13
// baseline (624.322 us; speedup 1.0000x reference)
//
#include <hip/hip_runtime.h>

typedef _Float16 f16;
typedef _Float16 f16x8 __attribute__((ext_vector_type(8)));
typedef float    f32x4 __attribute__((ext_vector_type(4)));

// ws layout (bytes)
#define OFF_WHP   0u          // f16 [5][16nt][8kk][64lane][8e]   = 655360 B
#define OFF_WLP   655360u     // f16 [8kk][64lane][8e]            = 8192 B
#define OFF_W0P   663552u     // f32 [8kk][64lane][8e][4i]        = 65536 B
#define OFF_B0P   729088u     // f32 [8kk][64lane][8e]            = 16384 B
#define OFF_GP    745472u     // f32 [3j][8kk][64lane][8e]        = 49152 B
#define OFF_BHP   794624u     // f32 [5l][16nt][64lane][4r]       = 81920 B

// k-slot map: slot (kk, lane-group g, elem e) -> k = (2kk+(e>>2))*16+4g+(e&3).
// Same map on A (prepacked weights) and B (activations): MFMA D-output
// (n = nt*16+4g+r) lands exactly in B-slot (kk'=nt>>1, e'=(nt&1)*4+r).
__device__ __forceinline__ int phi(int kk, int g, int e){
  return (kk*2 + (e>>2))*16 + g*4 + (e&3);
}

__device__ __forceinline__ float tanh_fast(float z){
  float e = __builtin_amdgcn_exp2f(z * 2.885390081777927f);
  return 1.f - 2.f*__builtin_amdgcn_rcpf(e + 1.f);
}

__global__ void prepack(const float* __restrict__ W0, const float* __restrict__ b0,
                        const float* __restrict__ Wh, const float* __restrict__ bh,
                        const float* __restrict__ Wl, unsigned char* __restrict__ ws){
  int tid = blockIdx.x*256 + threadIdx.x;
  f16*   whp = (f16*)(ws + OFF_WHP);
  f16*   wlp = (f16*)(ws + OFF_WLP);
  float* w0p = (float*)(ws + OFF_W0P);
  float* b0p = (float*)(ws + OFF_B0P);
  float* gp  = (float*)(ws + OFF_GP);
  float* bhp = (float*)(ws + OFF_BHP);
  if (tid < 327680){                      // Wh fragments, f16
    int e=tid&7, lane=(tid>>3)&63, kk=(tid>>9)&7, nt=(tid>>12)&15, l=tid>>16;
    int k = phi(kk, lane>>4, e);
    int n = nt*16 + (lane&15);
    whp[tid] = (f16)Wh[(l*256 + k)*256 + n];
  } else if (tid < 331776){               // Wl fragments (N padded 3->16), f16
    int t = tid - 327680;
    int e=t&7, lane=(t>>3)&63, kk=t>>9;
    int k = phi(kk, lane>>4, e);
    int n = lane&15;
    wlp[t] = (n<3) ? (f16)Wl[k*3+n] : (f16)0.f;
  } else if (tid < 335872){               // W0 columns + b0 in slot order, f32
    int t = tid - 331776;
    int e=t&7, lane=(t>>3)&63, kk=t>>9;
    int k = phi(kk, lane>>4, e);
    #pragma unroll
    for(int i=0;i<4;i++) w0p[t*4+i] = W0[i*256+k];
    b0p[t] = b0[k];
  } else if (tid < 348160){               // g_j = W0[j,:] @ Wh[0], slot order, f32
    int t = tid - 335872;
    int e=t&7, lane=(t>>3)&63, kk=(t>>9)&7, j=t>>12;
    int k = phi(kk, lane>>4, e);
    float acc = 0.f;
    for(int k0=0;k0<256;k0++) acc = fmaf(W0[j*256+k0], Wh[k0*256+k], acc);
    gp[t] = acc;
  } else if (tid < 368640){               // bh in D-layout order, f32
    int t = tid - 348160;
    int r=t&3, lane=(t>>2)&63, nt=(t>>8)&15, l=t>>12;
    bhp[t] = bh[l*256 + nt*16 + (lane>>4)*4 + r];
  }
}

// Lane-local chunk layout (writer lane == reader lane), XOR bank swizzle.
__device__ __forceinline__ int moff(int lane, int kk){
  return lane*128 + ((kk ^ (lane & 7)) << 4);
}

// R13: I-CACHE fix. Every kernel since R4 fully unrolled ~10k instructions
// (~60-80KB code, executed once per wave-pass, zero icache reuse: L1I=32KB).
// Explains the 330us plateau: MfmaUtil==VALUBusy~19% (issue starved by fetch),
// ALL data-path changes null (R9/R10/R11), TLP null (R12: 46% occ, worse).
// Fix: ROLL the nt-pair loop (#pragma unroll 1). Runtime-indexed register
// state is illegal (rule #20), so D-outputs round-trip through a per-wave
// lane-local LDS buffer (xbuf[wave], writer==reader, no extra barrier; masks
// double-buffered -> still 1 barrier/layer). Kernel body ~2-3KB, I-resident.
__global__ __launch_bounds__(256, 3) void velcurl(
    const float* __restrict__ x, const unsigned char* __restrict__ ws,
    float* __restrict__ out){
  __shared__ __align__(16) char xbuf[4][8192];   // [wave] own-chain D-outs (B-slot chunks)
  __shared__ __align__(16) char mbuf[2][8192];   // [parity] tanh' masks from wave0
  __shared__ float outt[3][3][16];               // [j][n][s] Jacobian rows

  const int lane  = threadIdx.x & 63;
  const int c     = threadIdx.x >> 6;   // 0 = primal, 1..3 = tangent j=c-1
  const int s     = lane & 15;
  const int sbase = blockIdx.x << 4;    // 16 samples per block

  const f16x8* __restrict__ whp = (const f16x8*)(ws + OFF_WHP);
  const f16x8* __restrict__ wlp = (const f16x8*)(ws + OFF_WLP);
  const f32x4* __restrict__ w0p = (const f32x4*)(ws + OFF_W0P);
  const float* __restrict__ b0p = (const float*)(ws + OFF_B0P);
  const float* __restrict__ gp  = (const float*)(ws + OFF_GP);
  const f32x4* __restrict__ bhp = (const f32x4*)(ws + OFF_BHP);

  char* const xbc = &xbuf[c][0];        // own exchange buffer
  f16x8 st[8];                          // only persistent register state

  #pragma unroll 1
  for(int p=0;p<5;p++){
    const f16x8* wl = whp + p*8192;
    // ---- phase A: build st (static kk indexing, small code) ----
    if (p==0){
      if (c==0){
        const f32x4 xv = ((const f32x4*)x)[sbase + s];
        #pragma unroll
        for(int kk=0;kk<8;kk++){
          f16x8 v;
          #pragma unroll
          for(int e=0;e<8;e++){
            f32x4 wv = w0p[(kk*64+lane)*8+e];
            float b  = b0p[(kk*64+lane)*8+e];
            v[e] = (f16)fmaf(xv[3],wv[3], fmaf(xv[2],wv[2], fmaf(xv[1],wv[1], fmaf(xv[0],wv[0], b))));
          }
          st[kk] = v;
        }
      }
    } else {
      const char* mb_prev = &mbuf[(p-1)&1][0];
      if (c==0){
        #pragma unroll
        for(int kk=0;kk<8;kk++)
          st[kk] = *(const f16x8*)(xbc + moff(lane, kk));
      } else if (p==1){
        const int j = c-1;
        const f32x4* gpv = (const f32x4*)gp;
        #pragma unroll
        for(int kk=0;kk<8;kk++){
          f16x8 m8 = *(const f16x8*)(mb_prev + moff(lane, kk));
          f32x4 g0 = gpv[((j*8+kk)*64+lane)*2+0];
          f32x4 g1 = gpv[((j*8+kk)*64+lane)*2+1];
          f16x8 v;
          #pragma unroll
          for(int e=0;e<8;e++){
            float gv = (e<4) ? g0[e&3] : g1[e&3];
            v[e] = (f16)((float)m8[e] * gv);
          }
          st[kk] = v;
        }
      } else {
        #pragma unroll
        for(int kk=0;kk<8;kk++){
          f16x8 m8 = *(const f16x8*)(mb_prev + moff(lane, kk));
          f16x8 x8 = *(const f16x8*)(xbc + moff(lane, kk));
          st[kk] = m8 * x8;
        }
      }
    }

    // ---- phase B: rolled nt-pair sweep (q=0..7), D-outs -> own LDS ----
    if (c==0){
      const f32x4* bp = bhp + p*1024;
      char* mb = &mbuf[p&1][0];
      #pragma unroll 1
      for(int q=0;q<8;q++){
        const f16x8* fp = wl + (2*q)*8*64 + lane;
        f32x4 a0 = {0.f,0.f,0.f,0.f}, a1 = {0.f,0.f,0.f,0.f};
        #pragma unroll
        for(int kk=0;kk<8;kk++){
          a0 = __builtin_amdgcn_mfma_f32_16x16x32_f16(fp[kk*64],     st[kk], a0, 0,0,0);
          a1 = __builtin_amdgcn_mfma_f32_16x16x32_f16(fp[(8+kk)*64], st[kk], a1, 0,0,0);
        }
        f32x4 b0v = bp[(2*q)*64+lane], b1v = bp[(2*q+1)*64+lane];
        f16x8 hv, mv;
        #pragma unroll
        for(int r=0;r<4;r++){
          float h0 = tanh_fast(a0[r]+b0v[r]);
          float h1 = tanh_fast(a1[r]+b1v[r]);
          hv[r] = (f16)h0;  hv[4+r] = (f16)h1;
          mv[r] = (f16)(1.f-h0*h0);  mv[4+r] = (f16)(1.f-h1*h1);
        }
        *(f16x8*)(xbc + moff(lane, q)) = hv;
        *(f16x8*)(mb  + moff(lane, q)) = mv;
      }
    } else if (p>=1){
      #pragma unroll 1
      for(int q=0;q<8;q++){
        const f16x8* fp = wl + (2*q)*8*64 + lane;
        f32x4 a0 = {0.f,0.f,0.f,0.f}, a1 = {0.f,0.f,0.f,0.f};
        #pragma unroll
        for(int kk=0;kk<8;kk++){
          a0 = __builtin_amdgcn_mfma_f32_16x16x32_f16(fp[kk*64],     st[kk], a0, 0,0,0);
          a1 = __builtin_amdgcn_mfma_f32_16x16x32_f16(fp[(8+kk)*64], st[kk], a1, 0,0,0);
        }
        f16x8 v;
        #pragma unroll
        for(int r=0;r<4;r++){ v[r] = (f16)a0[r]; v[4+r] = (f16)a1[r]; }
        *(f16x8*)(xbc + moff(lane, q)) = v;
      }
    }
    __syncthreads();   // masks(p) + all exchanges visible for phase A(p+1)
  }

  // ---- final layer: tangent waves, mask4 = mbuf[0] ((4)&1) ----
  if (c>0){
    const char* mb = &mbuf[0][0];
    f32x4 acc = {0.f,0.f,0.f,0.f};
    #pragma unroll
    for(int kk=0;kk<8;kk++){
      f16x8 m8 = *(const f16x8*)(mb + moff(lane, kk));
      f16x8 x8 = *(const f16x8*)(xbc + moff(lane, kk));
      acc = __builtin_amdgcn_mfma_f32_16x16x32_f16(wlp[kk*64+lane], m8*x8, acc, 0,0,0);
    }
    // D: col=lane&15=s, row=(lane>>4)*4+reg -> lanes 0..15 hold rows 0..3
    if (lane<16){
      outt[c-1][0][lane] = acc[0];
      outt[c-1][1][lane] = acc[1];
      outt[c-1][2][lane] = acc[2];
    }
  }
  __syncthreads();

  if (c==0 && lane<16){
    const int so = (sbase + lane)*3;
    out[so+0] = outt[1][2][lane] - outt[2][1][lane];  // da2/dx1 - da1/dx2
    out[so+1] = outt[2][0][lane] - outt[0][2][lane];  // da0/dx2 - da2/dx0
    out[so+2] = outt[0][1][lane] - outt[1][0][lane];  // da1/dx0 - da0/dx1
  }
}

extern "C" void kernel_launch(void* const* d_in, const int* in_sizes, int n_in,
                              void* d_out, int out_size, void* d_ws, size_t ws_size,
                              hipStream_t stream){
  const float* x  = (const float*)d_in[0];
  const float* W0 = (const float*)d_in[1];
  const float* b0 = (const float*)d_in[2];
  const float* Wh = (const float*)d_in[3];
  const float* bh = (const float*)d_in[4];
  const float* Wl = (const float*)d_in[5];
  // d_in[6] = bl: constant offset of a, curl kills it.
  prepack<<<1440, 256, 0, stream>>>(W0, b0, Wh, bh, Wl, (unsigned char*)d_ws);
  velcurl<<<4096, 256, 0, stream>>>(x, (const unsigned char*)d_ws, (float*)d_out);
}